// Round 20
// baseline (70.445 us; speedup 1.0000x reference)
//
#include <hip/hip_runtime.h>
#include <math.h>

typedef __bf16 bf16x8 __attribute__((ext_vector_type(8)));
typedef float f32x4 __attribute__((ext_vector_type(4)));
typedef unsigned short u16x8 __attribute__((ext_vector_type(8)));

#define N_TOT 8192
#define HALF_N 4096
#define D 128
#define INV_T 14.285714285714286f
#define CSC 20.609929155556627f    /* (1/0.07) * log2(e) */
#define NCSC -20.609929155556627f
#define LN2F 0.69314718055994531f
#define NEG_BIG -3.0e38f
#define M_INIT -1.0e30f
#define THR_RAW 1.0f                /* defer-max slack (raw units) */
#define CS 16                       /* col groups of 512 = 32 tiles */

__device__ __forceinline__ unsigned short f2bf(float f) {
    union { float f; unsigned int u; } a; a.f = f;
    unsigned int u = a.u;
    return (unsigned short)((u + 0x7fffu + ((u >> 16) & 1u)) >> 16);
}

// ---------- kernel 1: fp32 -> bf16 packed in MFMA-fragment order ----------
// fbP chunk c (16B): c = (T*4 + kk)*64 + lg*16 + lr  holds
// F[col = T*16 + lr][kk*32 + lg*8 .. +8]; a (tile,kk) wave-load is one
// contiguous 1KB read; 8 consecutive tiles are a contiguous 32 KB span.
// Block 0 also zero-inits the output accumulator and completion counters.
__global__ __launch_bounds__(256)
void cvt_kernel(const float* __restrict__ in, unsigned short* __restrict__ fbP,
                float* __restrict__ out, int* __restrict__ cnt) {
    if (blockIdx.x == 0) {
        if (threadIdx.x == 0) out[0] = 0.f;
        if (threadIdx.x < 32) cnt[threadIdx.x] = 0;
    }
    const int c   = blockIdx.x * 256 + threadIdx.x;
    const int q   = c >> 6;
    const int rem = c & 63;
    const int lg  = rem >> 4, lr = rem & 15;
    const int kk  = q & 3;
    const int col = (q >> 2) * 16 + lr;
    const int j16 = kk * 4 + lg;
    const float4 v0 = reinterpret_cast<const float4*>(in)[col * 32 + j16 * 2];
    const float4 v1 = reinterpret_cast<const float4*>(in)[col * 32 + j16 * 2 + 1];
    u16x8 o;
    o[0] = f2bf(v0.x); o[1] = f2bf(v0.y); o[2] = f2bf(v0.z); o[3] = f2bf(v0.w);
    o[4] = f2bf(v1.x); o[5] = f2bf(v1.y); o[6] = f2bf(v1.z); o[7] = f2bf(v1.w);
    reinterpret_cast<u16x8*>(fbP)[c] = o;
}

// ---------- kernel 2: fused sim + online logsumexp + last-block finalize ----------
// R19 structure verbatim (co-best, 36.8 us): grid (32 rowgroups, 16 colgroups),
// 256 thr = 4 waves, 2 blocks/CU (64 KB LDS). Wave w HOLDS rows
// [rg*256 + w*64, +64). Block stages 32 KB (8 col-tiles) per phase via
// global_load_lds (linear both sides), double-buffered; 4 loop barriers.
// NEW: the 16th (last) colgroup block of each rowgroup merges that rowgroup's
// partials in-kernel (release-fence + agent-scope acq_rel counter), removing
// the third dispatch; merge overlaps the simclr tail.
__global__ __launch_bounds__(256, 2)
void simclr_kernel(const unsigned short* __restrict__ fbP,
                   float* __restrict__ pm, float* __restrict__ ps,
                   float* __restrict__ rowpos, int* __restrict__ cnt,
                   float* __restrict__ out) {
    __shared__ __align__(16) unsigned short lds[2][16384];   // 2 x 32 KB
    const int tid  = threadIdx.x;
    const int lane = tid & 63;
    const int wid  = tid >> 6;              // 0..3
    const int lr   = lane & 15;
    const int lg   = lane >> 4;
    const int RT0  = blockIdx.x * 16 + wid * 4;   // first held row-tile
    const int Tw   = blockIdx.y * 32;             // first streamed col-tile

    // held rows: 4 row-tiles (distinct per wave), loaded once from L2
    bf16x8 br[4][4];
#pragma unroll
    for (int rt = 0; rt < 4; ++rt)
#pragma unroll
        for (int kk = 0; kk < 4; ++kk)
            br[rt][kk] = *reinterpret_cast<const bf16x8*>(
                fbP + ((size_t)(((RT0 + rt) * 4 + kk) * 64) + lane) * 8);

    float m[4], s[4];
#pragma unroll
    for (int rt = 0; rt < 4; ++rt) { m[rt] = M_INIT; s[rt] = 0.f; }

    // stage phase q's 32 KB (tiles Tw+8q .. +7) -> lds[b]: linear both sides
    auto stage = [&](int q, int b) {
#pragma unroll
        for (int h = 0; h < 8; ++h) {
            const unsigned short* src =
                fbP + ((size_t)(Tw + 8 * q) * 256 + h * 256 + tid) * 8;
            unsigned short* dst = &lds[b][(h * 256 + tid) * 8];
            __builtin_amdgcn_global_load_lds(
                (const __attribute__((address_space(1))) unsigned int*)(const void*)src,
                (__attribute__((address_space(3))) unsigned int*)(void*)dst,
                16, 0, 0);
        }
    };

    stage(0, 0);
    __syncthreads();

    int buf = 0;
#pragma unroll 1
    for (int q = 0; q < 4; ++q) {
        if (q < 3) stage(q + 1, buf ^ 1);   // 32 KB lands under 4 pair-computations

#pragma unroll
        for (int pp = 0; pp < 4; ++pp) {
            const unsigned short* B = &lds[buf][pp * 4096];
            bf16x8 ca[4], cb[4];
#pragma unroll
            for (int kk = 0; kk < 4; ++kk) {
                ca[kk] = *reinterpret_cast<const bf16x8*>(&B[(kk * 64 + lane) * 8]);
                cb[kk] = *reinterpret_cast<const bf16x8*>(&B[((kk + 4) * 64 + lane) * 8]);
            }

            const int c0 = blockIdx.y * 512 + (q * 8 + pp * 2) * 16;  // [c0, c0+32)

            f32x4 accP[4], accQ[4];
#pragma unroll
            for (int rt = 0; rt < 4; ++rt) accP[rt] = f32x4{0.f, 0.f, 0.f, 0.f};
#pragma unroll
            for (int kk = 0; kk < 4; ++kk)
#pragma unroll
                for (int rt = 0; rt < 4; ++rt)
                    accP[rt] = __builtin_amdgcn_mfma_f32_16x16x32_bf16(ca[kk], br[rt][kk], accP[rt], 0, 0, 0);
#pragma unroll
            for (int rt = 0; rt < 4; ++rt) accQ[rt] = f32x4{0.f, 0.f, 0.f, 0.f};
#pragma unroll
            for (int kk = 0; kk < 4; ++kk)
#pragma unroll
                for (int rt = 0; rt < 4; ++rt)
                    accQ[rt] = __builtin_amdgcn_mfma_f32_16x16x32_bf16(cb[kk], br[rt][kk], accQ[rt], 0, 0, 0);

            // merged pair epilogue: lane's elems = sim[rowbase+lr][c0 + lg*4+r (+16)]
#pragma unroll
            for (int rt = 0; rt < 4; ++rt) {
                const int rowbase = (RT0 + rt) * 16;
                f32x4 P = accP[rt], Q = accQ[rt];
                if (c0 == (rowbase ^ HALF_N)) {       // wave-uniform: positive tile
#pragma unroll
                    for (int r = 0; r < 4; ++r)
                        if (lr == lg * 4 + r) rowpos[rowbase + lr] = P[r];
                }
                if (c0 + 16 == (rowbase ^ HALF_N)) {
#pragma unroll
                    for (int r = 0; r < 4; ++r)
                        if (lr == lg * 4 + r) rowpos[rowbase + lr] = Q[r];
                }
                if (c0 == rowbase) {                  // wave-uniform: diagonal tile
#pragma unroll
                    for (int r = 0; r < 4; ++r)
                        if (lr == lg * 4 + r) P[r] = NEG_BIG;
                }
                if (c0 + 16 == rowbase) {
#pragma unroll
                    for (int r = 0; r < 4; ++r)
                        if (lr == lg * 4 + r) Q[r] = NEG_BIG;
                }
                const float t1 = fmaxf(fmaxf(P[0], P[1]), P[2]);
                const float t2 = fmaxf(fmaxf(P[3], Q[0]), Q[1]);
                const float t3 = fmaxf(Q[2], Q[3]);
                const float rmax = fmaxf(fmaxf(t1, t2), t3);
                // defer-max: rescale only when some lane exceeds m+THR
                if (!__all(rmax <= m[rt] + THR_RAW)) {
                    const float mn = fmaxf(m[rt], rmax);
                    s[rt] *= __builtin_amdgcn_exp2f(fmaf(m[rt], CSC, mn * NCSC));
                    m[rt] = mn;
                }
                const float cm = m[rt] * NCSC;
                const float e0 = __builtin_amdgcn_exp2f(fmaf(P[0], CSC, cm));
                const float e1 = __builtin_amdgcn_exp2f(fmaf(P[1], CSC, cm));
                const float e2 = __builtin_amdgcn_exp2f(fmaf(P[2], CSC, cm));
                const float e3 = __builtin_amdgcn_exp2f(fmaf(P[3], CSC, cm));
                const float e4 = __builtin_amdgcn_exp2f(fmaf(Q[0], CSC, cm));
                const float e5 = __builtin_amdgcn_exp2f(fmaf(Q[1], CSC, cm));
                const float e6 = __builtin_amdgcn_exp2f(fmaf(Q[2], CSC, cm));
                const float e7 = __builtin_amdgcn_exp2f(fmaf(Q[3], CSC, cm));
                s[rt] += ((e0 + e1) + (e2 + e3)) + ((e4 + e5) + (e6 + e7));
            }
        }

        __syncthreads();    // vmcnt(0)+barrier: next 32KB staged & reads done
        buf ^= 1;
    }

    // per-wave row-reduce: lanes sharing a row differ only in lg (xor 16,32)
#pragma unroll
    for (int rt = 0; rt < 4; ++rt) {
        float M = m[rt];
        M = fmaxf(M, __shfl_xor(M, 16, 64));
        M = fmaxf(M, __shfl_xor(M, 32, 64));
        float sc = s[rt] * __builtin_amdgcn_exp2f(fmaf(m[rt], CSC, M * NCSC));
        sc += __shfl_xor(sc, 16, 64);
        sc += __shfl_xor(sc, 32, 64);
        if (lg == 0) {
            const int row = (RT0 + rt) * 16 + lr;
            pm[blockIdx.y * N_TOT + row] = M;
            ps[blockIdx.y * N_TOT + row] = sc;
        }
    }

    // ---- completion protocol: last colgroup block of this rowgroup merges ----
    __threadfence();                    // release my pm/ps/rowpos stores (agent scope)
    __syncthreads();                    // all waves' stores flushed
    __shared__ int sOld;
    if (tid == 0)
        sOld = __hip_atomic_fetch_add(&cnt[blockIdx.x], 1,
                                      __ATOMIC_ACQ_REL, __HIP_MEMORY_SCOPE_AGENT);
    __syncthreads();
    if (sOld == CS - 1) {
        // acquire side: 15 prior releases happen-before this block's loads
        const int row = blockIdx.x * 256 + tid;
        float M = pm[row], S = ps[row];
#pragma unroll
        for (int c = 1; c < CS; ++c) {
            const float Mo = pm[c * N_TOT + row], So = ps[c * N_TOT + row];
            const float mn = fmaxf(M, Mo);
            S = fmaf(S,  __builtin_amdgcn_exp2f(fmaf(M,  CSC, mn * NCSC)),
                     So * __builtin_amdgcn_exp2f(fmaf(Mo, CSC, mn * NCSC)));
            M = mn;
        }
        float acc = LN2F * fmaf(M, CSC, __builtin_amdgcn_logf(S)) - rowpos[row] * INV_T;
#pragma unroll
        for (int off = 32; off > 0; off >>= 1) acc += __shfl_xor(acc, off, 64);
        __shared__ float ls[4];
        if ((tid & 63) == 0) ls[tid >> 6] = acc;
        __syncthreads();
        if (tid == 0)
            atomicAdd(out, (ls[0] + ls[1] + ls[2] + ls[3]) * (1.0f / (float)N_TOT));
    }
}

extern "C" void kernel_launch(void* const* d_in, const int* in_sizes, int n_in,
                              void* d_out, int out_size, void* d_ws, size_t ws_size,
                              hipStream_t stream) {
    const float* feat = (const float*)d_in[0];
    char* ws = (char*)d_ws;
    unsigned short* fbP = (unsigned short*)ws;                                  // 2 MB
    float* pm      = (float*)(ws + (size_t)N_TOT * D * 2);                      // 512 KB
    float* ps      = (float*)(ws + (size_t)N_TOT * D * 2 + (size_t)CS * N_TOT * 4);       // 512 KB
    float* rowpos  = (float*)(ws + (size_t)N_TOT * D * 2 + 2 * (size_t)CS * N_TOT * 4);   // 32 KB
    int*   cnt     = (int*)(ws + (size_t)N_TOT * D * 2 + 2 * (size_t)CS * N_TOT * 4 + N_TOT * 4);
    float* out = (float*)d_out;

    cvt_kernel<<<512, 256, 0, stream>>>(feat, fbP, out, cnt);
    simclr_kernel<<<dim3(32, CS), 256, 0, stream>>>(fbP, pm, ps, rowpos, cnt, out);
}

// Round 21
// 36.658 us; speedup vs baseline: 1.9217x; 1.9217x over previous
//
#include <hip/hip_runtime.h>
#include <math.h>

typedef __bf16 bf16x8 __attribute__((ext_vector_type(8)));
typedef float f32x4 __attribute__((ext_vector_type(4)));
typedef unsigned short u16x8 __attribute__((ext_vector_type(8)));

#define N_TOT 8192
#define HALF_N 4096
#define D 128
#define INV_T 14.285714285714286f
#define CSC 20.609929155556627f    /* (1/0.07) * log2(e) */
#define NCSC -20.609929155556627f
#define LN2F 0.69314718055994531f
#define NEG_BIG -3.0e38f
#define M_INIT -1.0e30f
#define THR_RAW 1.0f                /* defer-max slack (raw units) */
#define CS 16                       /* col groups of 512 = 32 tiles */

__device__ __forceinline__ unsigned short f2bf(float f) {
    union { float f; unsigned int u; } a; a.f = f;
    unsigned int u = a.u;
    return (unsigned short)((u + 0x7fffu + ((u >> 16) & 1u)) >> 16);
}

// ---------- kernel 1: fp32 -> bf16 packed in MFMA-fragment order ----------
// fbP chunk c (16B): c = (T*4 + kk)*64 + lg*16 + lr  holds
// F[col = T*16 + lr][kk*32 + lg*8 .. +8]; a (tile,kk) wave-load is one
// contiguous 1KB read; 8 consecutive tiles are a contiguous 32 KB span.
// Thread (0,0) zero-inits the output accumulator (replaces memset node).
__global__ __launch_bounds__(256)
void cvt_kernel(const float* __restrict__ in, unsigned short* __restrict__ fbP,
                float* __restrict__ out) {
    if (blockIdx.x == 0 && threadIdx.x == 0) out[0] = 0.f;
    const int c   = blockIdx.x * 256 + threadIdx.x;
    const int q   = c >> 6;
    const int rem = c & 63;
    const int lg  = rem >> 4, lr = rem & 15;
    const int kk  = q & 3;
    const int col = (q >> 2) * 16 + lr;
    const int j16 = kk * 4 + lg;
    const float4 v0 = reinterpret_cast<const float4*>(in)[col * 32 + j16 * 2];
    const float4 v1 = reinterpret_cast<const float4*>(in)[col * 32 + j16 * 2 + 1];
    u16x8 o;
    o[0] = f2bf(v0.x); o[1] = f2bf(v0.y); o[2] = f2bf(v0.z); o[3] = f2bf(v0.w);
    o[4] = f2bf(v1.x); o[5] = f2bf(v1.y); o[6] = f2bf(v1.z); o[7] = f2bf(v1.w);
    reinterpret_cast<u16x8*>(fbP)[c] = o;
}

// ---------- kernel 2: fused sim + online logsumexp, 32KB staging phases ----------
// Best-measured structure (36.8 us): grid (32 rowgroups, 16 colgroups), 256
// thr = 4 waves, 2 blocks/CU (64 KB LDS). Wave w HOLDS rows [rg*256+w*64,+64).
// Block stages 32 KB (8 col-tiles) per phase via global_load_lds (linear both
// sides), double-buffered; one __syncthreads per phase (barrier-drain ladder
// flat point: 32/16/8/4 drains -> 49.9/42.8/40.5/36.8 us total).
__global__ __launch_bounds__(256, 2)
void simclr_kernel(const unsigned short* __restrict__ fbP,
                   float* __restrict__ pm, float* __restrict__ ps,
                   float* __restrict__ rowpos) {
    __shared__ __align__(16) unsigned short lds[2][16384];   // 2 x 32 KB
    const int tid  = threadIdx.x;
    const int lane = tid & 63;
    const int wid  = tid >> 6;              // 0..3
    const int lr   = lane & 15;
    const int lg   = lane >> 4;
    const int RT0  = blockIdx.x * 16 + wid * 4;   // first held row-tile
    const int Tw   = blockIdx.y * 32;             // first streamed col-tile

    // held rows: 4 row-tiles (distinct per wave), loaded once from L2
    bf16x8 br[4][4];
#pragma unroll
    for (int rt = 0; rt < 4; ++rt)
#pragma unroll
        for (int kk = 0; kk < 4; ++kk)
            br[rt][kk] = *reinterpret_cast<const bf16x8*>(
                fbP + ((size_t)(((RT0 + rt) * 4 + kk) * 64) + lane) * 8);

    float m[4], s[4];
#pragma unroll
    for (int rt = 0; rt < 4; ++rt) { m[rt] = M_INIT; s[rt] = 0.f; }

    // stage phase q's 32 KB (tiles Tw+8q .. +7) -> lds[b]: linear both sides
    auto stage = [&](int q, int b) {
#pragma unroll
        for (int h = 0; h < 8; ++h) {
            const unsigned short* src =
                fbP + ((size_t)(Tw + 8 * q) * 256 + h * 256 + tid) * 8;
            unsigned short* dst = &lds[b][(h * 256 + tid) * 8];
            __builtin_amdgcn_global_load_lds(
                (const __attribute__((address_space(1))) unsigned int*)(const void*)src,
                (__attribute__((address_space(3))) unsigned int*)(void*)dst,
                16, 0, 0);
        }
    };

    stage(0, 0);
    __syncthreads();

    int buf = 0;
#pragma unroll 1
    for (int q = 0; q < 4; ++q) {
        if (q < 3) stage(q + 1, buf ^ 1);   // 32 KB lands under 4 pair-computations

#pragma unroll
        for (int pp = 0; pp < 4; ++pp) {
            const unsigned short* B = &lds[buf][pp * 4096];
            bf16x8 ca[4], cb[4];
#pragma unroll
            for (int kk = 0; kk < 4; ++kk) {
                ca[kk] = *reinterpret_cast<const bf16x8*>(&B[(kk * 64 + lane) * 8]);
                cb[kk] = *reinterpret_cast<const bf16x8*>(&B[((kk + 4) * 64 + lane) * 8]);
            }

            const int c0 = blockIdx.y * 512 + (q * 8 + pp * 2) * 16;  // [c0, c0+32)

            f32x4 accP[4], accQ[4];
#pragma unroll
            for (int rt = 0; rt < 4; ++rt) accP[rt] = f32x4{0.f, 0.f, 0.f, 0.f};
#pragma unroll
            for (int kk = 0; kk < 4; ++kk)
#pragma unroll
                for (int rt = 0; rt < 4; ++rt)
                    accP[rt] = __builtin_amdgcn_mfma_f32_16x16x32_bf16(ca[kk], br[rt][kk], accP[rt], 0, 0, 0);
#pragma unroll
            for (int rt = 0; rt < 4; ++rt) accQ[rt] = f32x4{0.f, 0.f, 0.f, 0.f};
#pragma unroll
            for (int kk = 0; kk < 4; ++kk)
#pragma unroll
                for (int rt = 0; rt < 4; ++rt)
                    accQ[rt] = __builtin_amdgcn_mfma_f32_16x16x32_bf16(cb[kk], br[rt][kk], accQ[rt], 0, 0, 0);

            // merged pair epilogue: lane's elems = sim[rowbase+lr][c0 + lg*4+r (+16)]
#pragma unroll
            for (int rt = 0; rt < 4; ++rt) {
                const int rowbase = (RT0 + rt) * 16;
                f32x4 P = accP[rt], Q = accQ[rt];
                if (c0 == (rowbase ^ HALF_N)) {       // wave-uniform: positive tile
#pragma unroll
                    for (int r = 0; r < 4; ++r)
                        if (lr == lg * 4 + r) rowpos[rowbase + lr] = P[r];
                }
                if (c0 + 16 == (rowbase ^ HALF_N)) {
#pragma unroll
                    for (int r = 0; r < 4; ++r)
                        if (lr == lg * 4 + r) rowpos[rowbase + lr] = Q[r];
                }
                if (c0 == rowbase) {                  // wave-uniform: diagonal tile
#pragma unroll
                    for (int r = 0; r < 4; ++r)
                        if (lr == lg * 4 + r) P[r] = NEG_BIG;
                }
                if (c0 + 16 == rowbase) {
#pragma unroll
                    for (int r = 0; r < 4; ++r)
                        if (lr == lg * 4 + r) Q[r] = NEG_BIG;
                }
                const float t1 = fmaxf(fmaxf(P[0], P[1]), P[2]);
                const float t2 = fmaxf(fmaxf(P[3], Q[0]), Q[1]);
                const float t3 = fmaxf(Q[2], Q[3]);
                const float rmax = fmaxf(fmaxf(t1, t2), t3);
                // defer-max: rescale only when some lane exceeds m+THR
                if (!__all(rmax <= m[rt] + THR_RAW)) {
                    const float mn = fmaxf(m[rt], rmax);
                    s[rt] *= __builtin_amdgcn_exp2f(fmaf(m[rt], CSC, mn * NCSC));
                    m[rt] = mn;
                }
                const float cm = m[rt] * NCSC;
                const float e0 = __builtin_amdgcn_exp2f(fmaf(P[0], CSC, cm));
                const float e1 = __builtin_amdgcn_exp2f(fmaf(P[1], CSC, cm));
                const float e2 = __builtin_amdgcn_exp2f(fmaf(P[2], CSC, cm));
                const float e3 = __builtin_amdgcn_exp2f(fmaf(P[3], CSC, cm));
                const float e4 = __builtin_amdgcn_exp2f(fmaf(Q[0], CSC, cm));
                const float e5 = __builtin_amdgcn_exp2f(fmaf(Q[1], CSC, cm));
                const float e6 = __builtin_amdgcn_exp2f(fmaf(Q[2], CSC, cm));
                const float e7 = __builtin_amdgcn_exp2f(fmaf(Q[3], CSC, cm));
                s[rt] += ((e0 + e1) + (e2 + e3)) + ((e4 + e5) + (e6 + e7));
            }
        }

        __syncthreads();    // vmcnt(0)+barrier: next 32KB staged & reads done
        buf ^= 1;
    }

    // per-wave row-reduce: lanes sharing a row differ only in lg (xor 16,32)
#pragma unroll
    for (int rt = 0; rt < 4; ++rt) {
        float M = m[rt];
        M = fmaxf(M, __shfl_xor(M, 16, 64));
        M = fmaxf(M, __shfl_xor(M, 32, 64));
        float sc = s[rt] * __builtin_amdgcn_exp2f(fmaf(m[rt], CSC, M * NCSC));
        sc += __shfl_xor(sc, 16, 64);
        sc += __shfl_xor(sc, 32, 64);
        if (lg == 0) {
            const int row = (RT0 + rt) * 16 + lr;
            pm[blockIdx.y * N_TOT + row] = M;
            ps[blockIdx.y * N_TOT + row] = sc;
        }
    }
}

// ---------- kernel 3: merge col-group partials, row loss, mean (32 blocks) ----------
__global__ __launch_bounds__(256)
void rowloss_mean_kernel(const float* __restrict__ pm, const float* __restrict__ ps,
                         const float* __restrict__ rowpos, float* __restrict__ out) {
    const int row = blockIdx.x * 256 + threadIdx.x;
    float M = pm[row], S = ps[row];
#pragma unroll
    for (int c = 1; c < CS; ++c) {
        const float Mo = pm[c * N_TOT + row], So = ps[c * N_TOT + row];
        const float mn = fmaxf(M, Mo);
        S = fmaf(S,  __builtin_amdgcn_exp2f(fmaf(M,  CSC, mn * NCSC)),
                 So * __builtin_amdgcn_exp2f(fmaf(Mo, CSC, mn * NCSC)));
        M = mn;
    }
    float acc = LN2F * fmaf(M, CSC, __builtin_amdgcn_logf(S)) - rowpos[row] * INV_T;
#pragma unroll
    for (int off = 32; off > 0; off >>= 1) acc += __shfl_xor(acc, off, 64);
    __shared__ float ls[4];
    if ((threadIdx.x & 63) == 0) ls[threadIdx.x >> 6] = acc;
    __syncthreads();
    if (threadIdx.x == 0)
        atomicAdd(out, (ls[0] + ls[1] + ls[2] + ls[3]) * (1.0f / (float)N_TOT));
}

extern "C" void kernel_launch(void* const* d_in, const int* in_sizes, int n_in,
                              void* d_out, int out_size, void* d_ws, size_t ws_size,
                              hipStream_t stream) {
    const float* feat = (const float*)d_in[0];
    char* ws = (char*)d_ws;
    unsigned short* fbP = (unsigned short*)ws;                                  // 2 MB
    float* pm      = (float*)(ws + (size_t)N_TOT * D * 2);                      // 512 KB
    float* ps      = (float*)(ws + (size_t)N_TOT * D * 2 + (size_t)CS * N_TOT * 4);       // 512 KB
    float* rowpos  = (float*)(ws + (size_t)N_TOT * D * 2 + 2 * (size_t)CS * N_TOT * 4);   // 32 KB
    float* out = (float*)d_out;

    cvt_kernel<<<512, 256, 0, stream>>>(feat, fbP, out);
    simclr_kernel<<<dim3(32, CS), 256, 0, stream>>>(fbP, pm, ps, rowpos);
    rowloss_mean_kernel<<<N_TOT / 256, 256, 0, stream>>>(pm, ps, rowpos, out);
}